// Round 13
// baseline (335.873 us; speedup 1.0000x reference)
//
#include <hip/hip_runtime.h>

// EncoderTreeRNN — R13: BARRIER-FREE tree kernel (R12 with cvt_pkrtz compile fix).
// Each wave owns 32 rows x 128 cols with a private LDS tile; no __syncthreads anywhere.
// Tree (word=0): z=sigm(hl Uzl+hr Uzr+bz), r=sigm(hl Url+hr Urr+br),
//                h~=tanh((r*hl)Uhl+(r*hr)Uhr+bh), out=z*(hl+hr)+(1-z)*h~
// K interleaved (k'=2j -> hl[j], 2j+1 -> hr[j]); U rows permuted to match.
// U frag layout (32x32): Uf[((cg*16+ks)*64+l)*8+j] = U'[ks*16+(l>>5)*8+j][cg*32+(l&31)].
// C/D: col=lane&31, row=(reg&3)+8*(reg>>2)+4*(lane>>5).

typedef _Float16 half_t;
typedef __attribute__((ext_vector_type(2))) _Float16 f16x2;
typedef __attribute__((ext_vector_type(8))) _Float16 f16x8;
typedef __attribute__((ext_vector_type(4))) float f32x4;
typedef __attribute__((ext_vector_type(16))) float f32x16;

#define NTOK 262144
#define NB 4096
#define NV 100000

__device__ __forceinline__ float sigm(float x){
  float e = __expf(-x);
  return __builtin_amdgcn_rcpf(1.0f + e);
}
// tanh(x) = 1 - 2/(1+e^{2x}); saturates, no clamp needed.
__device__ __forceinline__ float tanh_(float x){
  float e = __expf(2.f*x);
  float r = __builtin_amdgcn_rcpf(1.0f + e);
  return __builtin_fmaf(-2.0f, r, 1.0f);
}

__global__ void bias_k(const float* bWz,const float* bUzl,const float* bUzr,
                       const float* bWr,const float* bUrl,const float* bUrr,
                       const float* bWh,const float* bUhl,const float* bUhr, float* bc){
  int j = threadIdx.x;
  if (j < 128)      bc[j] = bWz[j]+bUzl[j]+bUzr[j];
  else if (j < 256){ int i=j-128; bc[j] = bWr[i]+bUrl[i]+bUrr[i]; }
  else if (j < 384){ int i=j-256; bc[j] = bWh[i]+bUhl[i]+bUhr[i]; }
}

// W (16x16 frag, K=128): Wf[((w*4+ks)*64+l)*8+j] = W[ks*32+(l>>4)*8+j][w*16+(l&15)]
// U (32x32 frag, K=256 interleaved): see header.
__global__ __launch_bounds__(256) void wprep_k(
    const float* Wz, const float* Wh,
    const float* Uzl,const float* Uzr,const float* Url,const float* Urr,
    const float* Uhl,const float* Uhr, half_t* wb){
  int idx = blockIdx.x*256 + threadIdx.x;           // 131072 total
  if (idx < 32768){                                  // Wz_f, Wh_f (16x16 layout)
    const float* W = (idx < 16384) ? Wz : Wh;
    int t = idx & 16383;
    int w = t >> 11, ks = (t >> 9) & 3, l = (t >> 3) & 63, j = t & 7;
    int n = w*16 + (l & 15);
    int k = ks*32 + ((l >> 4) << 3) + j;
    wb[idx] = (half_t)W[k*128 + n];
  } else {                                           // Uz_f, Ur_f, Uh_f (32x32 layout)
    int t = idx - 32768;
    int mat = t >> 15;                               // 0=z,1=r,2=h
    t &= 32767;
    int cg = t >> 13, ks = (t >> 9) & 15, l = (t >> 3) & 63, j = t & 7;
    int n = cg*32 + (l & 31);
    int kp = ks*16 + ((l >> 5) << 3) + j;            // 0..255 interleaved
    int k = kp >> 1;
    const float* U;
    if (mat == 0) U = (kp & 1) ? Uzr : Uzl;
    else if (mat == 1) U = (kp & 1) ? Urr : Url;
    else U = (kp & 1) ? Uhr : Uhl;
    wb[idx] = (half_t)U[k*128 + n];
  }
}

// Vocab table (16x16 path): t1[v] = (1-z)*tanh(xWh+bh), z=sigm(xWz+bz). Sequential rows.
template<int MT>
__global__ __launch_bounds__(512, 8) void h1tab_k(
    const float* __restrict__ emb,
    const half_t* __restrict__ Wz_f, const half_t* __restrict__ Wh_f,
    const float* __restrict__ bc, half_t* __restrict__ t1)
{
  __shared__ __align__(16) _Float16 xs[MT*16][136];
  const int tid = threadIdx.x;
  const int m0  = blockIdx.x*(MT*16);
  #pragma unroll
  for (int it = 0; it < MT; it++){
    int idx = it*512 + tid;
    int m = idx >> 5, c = idx & 31;
    int row = m0 + m; if (row >= NV) row = 0;
    float4 v = ((const float4*)(emb + (size_t)row*128))[c];
    union { half_t h[4]; ushort4 u; } p;
    p.h[0]=(half_t)v.x; p.h[1]=(half_t)v.y; p.h[2]=(half_t)v.z; p.h[3]=(half_t)v.w;
    *(ushort4*)&xs[m][c*4] = p.u;
  }
  __syncthreads();
  const int w = tid>>6, l = tid&63;
  const int lr = l&15, lk = (l>>4)*8, lq = (l>>4)*4;
  const int col = w*16 + lr;

  f32x4 zacc[MT] = {}; f32x4 hacc[MT] = {};
  const half_t* wzp = Wz_f + ((w*4)*64 + l)*8;
  const half_t* whp = Wh_f + ((w*4)*64 + l)*8;
  #pragma unroll
  for (int ks=0; ks<4; ks++){
    f16x8 bz = *(const f16x8*)(wzp + ks*512);
    f16x8 bh = *(const f16x8*)(whp + ks*512);
    #pragma unroll
    for (int mt=0; mt<MT; mt++){
      f16x8 a = *(const f16x8*)&xs[mt*16 + lr][ks*32 + lk];
      zacc[mt] = __builtin_amdgcn_mfma_f32_16x16x32_f16(a, bz, zacc[mt],0,0,0);
      hacc[mt] = __builtin_amdgcn_mfma_f32_16x16x32_f16(a, bh, hacc[mt],0,0,0);
    }
  }
  const float bzv = bc[col], bhv = bc[256+col];
  #pragma unroll
  for (int mt=0; mt<MT; mt++){
    #pragma unroll
    for (int q=0; q<4; q++){
      int row = m0 + mt*16 + lq + q;
      if (row < NV){
        float z  = sigm(zacc[mt][q] + bzv);
        float ht = tanh_(hacc[mt][q] + bhv);
        t1[(size_t)row*128 + col] = (half_t)((1.f-z)*ht);
      }
    }
  }
}

// Barrier-free tree level. 256 thr = 4 INDEPENDENT waves; wave owns 32 rows, all 128 cols.
template<int GATHER>
__global__ __launch_bounds__(256) void tree_k(
    const half_t* __restrict__ hin, const int* __restrict__ tokens,
    half_t* __restrict__ hout, float* __restrict__ outf,
    const half_t* __restrict__ Uz_f, const half_t* __restrict__ Ur_f, const half_t* __restrict__ Uh_f,
    const float* __restrict__ bc, int last)
{
  __shared__ __align__(16) _Float16 xs[4][32][264];   // 16.9 KB per wave, private
  const int tid = threadIdx.x;
  const int w = tid >> 6, l = tid & 63;
  const int m0 = (blockIdx.x*4 + w) * 32;             // this wave's 32 output rows
  _Float16 (*tile)[264] = xs[w];

  // --- stage own tile, interleaved {hl,hr}: tile[m][2j]=hl[j], tile[m][2j+1]=hr[j] ---
  #pragma unroll
  for (int it = 0; it < 16; it++){
    int idx = it*64 + l;            // 32 rows x 32 uint4-chunks
    int m = idx >> 5, c = idx & 31;
    const half_t *pl, *pr;
    if (GATHER){
      int tl = tokens[2*(m0+m)], tr = tokens[2*(m0+m)+1];
      pl = hin + (size_t)tl*128 + c*4;
      pr = hin + (size_t)tr*128 + c*4;
    } else {
      size_t base = (size_t)(2*(m0+m))*128 + c*4;
      pl = hin + base;
      pr = hin + base + 128;
    }
    uint2 A  = *(const uint2*)pl;
    uint2 Bv = *(const uint2*)pr;
    uint4 o;
    o.x = (A.x & 0xFFFFu) | (Bv.x << 16);
    o.y = (A.x >> 16)     | (Bv.x & 0xFFFF0000u);
    o.z = (A.y & 0xFFFFu) | (Bv.y << 16);
    o.w = (A.y >> 16)     | (Bv.y & 0xFFFF0000u);
    *(uint4*)&tile[m][c*8] = o;
  }
  // no barrier: lgkmcnt/vmcnt dependencies are wave-internal

  const int lc = l & 31, hi = l >> 5;
  const int lk8 = hi*8;

  // --- phase 1: z & r GEMMs + activations per col-group; keep z, rv packed f16x2 ---
  f16x2 zs[32], rv[32];
  #pragma unroll
  for (int cg = 0; cg < 4; cg++){
    f32x16 zacc = {}; f32x16 racc = {};
    const half_t* uzp = Uz_f + ((cg*16)*64 + l)*8;
    const half_t* urp = Ur_f + ((cg*16)*64 + l)*8;
    #pragma unroll
    for (int ks=0; ks<16; ks++){
      f16x8 bz = *(const f16x8*)(uzp + ks*512);
      f16x8 br = *(const f16x8*)(urp + ks*512);
      f16x8 a = *(const f16x8*)&tile[lc][ks*16 + lk8];
      zacc = __builtin_amdgcn_mfma_f32_32x32x16_f16(a, bz, zacc,0,0,0);
      racc = __builtin_amdgcn_mfma_f32_32x32x16_f16(a, br, racc,0,0,0);
    }
    const int col = cg*32 + lc;
    const float bzv = bc[col], brv = bc[128+col];
    #pragma unroll
    for (int p = 0; p < 8; p++){
      f16x2 zv2, rv2;
      zv2[0] = (half_t)sigm(zacc[2*p]   + bzv);
      zv2[1] = (half_t)sigm(zacc[2*p+1] + bzv);
      rv2[0] = (half_t)sigm(racc[2*p]   + brv);
      rv2[1] = (half_t)sigm(racc[2*p+1] + brv);
      zs[cg*8+p] = zv2;
      rv[cg*8+p] = rv2;
    }
  }

  // --- writeback: r*hl, r*hr into tile (raw h no longer needed); pack s = hl+hr ---
  f16x2 sp[32];
  #pragma unroll
  for (int cg = 0; cg < 4; cg++){
    const int col = cg*32 + lc;
    #pragma unroll
    for (int p = 0; p < 8; p++){
      half_t s01[2];
      #pragma unroll
      for (int e = 0; e < 2; e++){
        int r = 2*p + e;
        int row = (r&3) + 8*(r>>2) + 4*hi;
        union { uint u; f16x2 h2; } io;
        io.u = *(uint*)&tile[row][2*col];
        s01[e] = (half_t)(io.h2[0] + io.h2[1]);
        half_t rvh = rv[cg*8+p][e];
        f16x2 rv2; rv2[0]=rvh; rv2[1]=rvh;
        io.h2 = io.h2 * rv2;                 // v_pk_mul_f16
        *(uint*)&tile[row][2*col] = io.u;
      }
      f16x2 sv; sv[0]=s01[0]; sv[1]=s01[1];
      sp[cg*8+p] = sv;
    }
  }

  // --- phase 2: h~ GEMM per col-group + epilogue ---
  #pragma unroll
  for (int cg = 0; cg < 4; cg++){
    f32x16 hacc = {};
    const half_t* uhp = Uh_f + ((cg*16)*64 + l)*8;
    #pragma unroll
    for (int ks=0; ks<16; ks++){
      f16x8 bh = *(const f16x8*)(uhp + ks*512);
      f16x8 a = *(const f16x8*)&tile[lc][ks*16 + lk8];
      hacc = __builtin_amdgcn_mfma_f32_32x32x16_f16(a, bh, hacc,0,0,0);
    }
    const int col = cg*32 + lc;
    const float bhv = bc[256+col];
    #pragma unroll
    for (int p = 0; p < 8; p++){
      #pragma unroll
      for (int e = 0; e < 2; e++){
        int r = 2*p + e;
        int row = (r&3) + 8*(r>>2) + 4*hi;
        float ht = tanh_(hacc[r] + bhv);
        float z  = (float)zs[cg*8+p][e];
        float s  = (float)sp[cg*8+p][e];
        float o  = __builtin_fmaf(z, s - ht, ht);
        size_t off = (size_t)(m0+row)*128 + col;
        if (last) outf[off] = o;
        else      hout[off] = (half_t)o;
      }
    }
  }
}

extern "C" void kernel_launch(void* const* d_in, const int* in_sizes, int n_in,
                              void* d_out, int out_size, void* d_ws, size_t ws_size,
                              hipStream_t stream) {
  const int*   tokens = (const int*)  d_in[0];
  const float* emb    = (const float*)d_in[1];
  const float* Wz  = (const float*)d_in[2];  const float* bWz  = (const float*)d_in[3];
  const float* Uzl = (const float*)d_in[4];  const float* bUzl = (const float*)d_in[5];
  const float* Uzr = (const float*)d_in[6];  const float* bUzr = (const float*)d_in[7];
  const float* Wr  = (const float*)d_in[8];  const float* bWr  = (const float*)d_in[9];
  const float* Url = (const float*)d_in[10]; const float* bUrl = (const float*)d_in[11];
  const float* Urr = (const float*)d_in[12]; const float* bUrr = (const float*)d_in[13];
  const float* Wh  = (const float*)d_in[14]; const float* bWh  = (const float*)d_in[15];
  const float* Uhl = (const float*)d_in[16]; const float* bUhl = (const float*)d_in[17];
  const float* Uhr = (const float*)d_in[18]; const float* bUhr = (const float*)d_in[19];

  float*  bc = (float*)d_ws;
  half_t* wb = (half_t*)((char*)d_ws + 4096);
  half_t* Wz_f = wb;
  half_t* Wh_f = wb + 16384;
  half_t* Uz_f = wb + 32768;
  half_t* Ur_f = wb + 65536;
  half_t* Uh_f = wb + 98304;
  half_t* t1 = (half_t*)((char*)d_ws + (1<<20));     // 100000*128 f16 = 25.6 MB
  half_t* hA = t1 + (size_t)NV*128;                  // 131072*128 f16 = 33.5 MB
  half_t* hB = hA + (size_t)(NTOK/2)*128;            // 65536*128 f16 = 16.8 MB

  bias_k<<<1, 384, 0, stream>>>(bWz,bUzl,bUzr,bWr,bUrl,bUrr,bWh,bUhl,bUhr, bc);
  wprep_k<<<512, 256, 0, stream>>>(Wz,Wh,Uzl,Uzr,Url,Urr,Uhl,Uhr, wb);

  h1tab_k<4><<<(NV + 63)/64, 512, 0, stream>>>(emb, Wz_f, Wh_f, bc, t1);

  float* outf = (float*)d_out;
  // barrier-free: grid = M/128 blocks of 4 independent waves (32 rows each)
  tree_k<1><<<1024, 256, 0, stream>>>(t1, tokens, hA, outf, Uz_f, Ur_f, Uh_f, bc, 0); // L1 131072
  tree_k<0><<<512,  256, 0, stream>>>(hA, tokens, hB, outf, Uz_f, Ur_f, Uh_f, bc, 0); // L2 65536
  tree_k<0><<<256,  256, 0, stream>>>(hB, tokens, hA, outf, Uz_f, Ur_f, Uh_f, bc, 0); // L3 32768
  tree_k<0><<<128,  256, 0, stream>>>(hA, tokens, hB, outf, Uz_f, Ur_f, Uh_f, bc, 0); // L4 16384
  tree_k<0><<<64,   256, 0, stream>>>(hB, tokens, hA, outf, Uz_f, Ur_f, Uh_f, bc, 0); // L5 8192
  tree_k<0><<<32,   256, 0, stream>>>(hA, tokens, hB, outf, Uz_f, Ur_f, Uh_f, bc, 1); // L6 4096 -> f32
}

// Round 14
// 166.128 us; speedup vs baseline: 2.0218x; 2.0218x over previous
//
#include <hip/hip_runtime.h>

// EncoderTreeRNN — R14: two-tile software-pipelined tree kernel (phase mixing in-stream)
// + pair-interleaved inter-level h format (staging = plain copy for L2..L6).
// Tree (word=0): z=sigm(hl Uzl+hr Uzr+bz), r=sigm(hl Url+hr Urr+br),
//                h~=tanh((r*hl)Uhl+(r*hr)Uhr+bh), out=z*(hl+hr)+(1-z)*h~
// K interleaved (k'=2j -> hl[j], 2j+1 -> hr[j]); U rows permuted to match.
// U frag layout (32x32): Uf[((cg*16+ks)*64+l)*8+j] = U'[ks*16+(l>>5)*8+j][cg*32+(l&31)].
// C/D: col=lane&31, row=(reg&3)+8*(reg>>2)+4*(lane>>5).
// Inter-level buffer: pair-row p holds u32 {h[2p][col], h[2p+1][col]} at [p*128+col] (u32 units);
// next level's 32-row tile = contiguous 16KB copy.

typedef _Float16 half_t;
typedef __attribute__((ext_vector_type(2))) _Float16 f16x2;
typedef __attribute__((ext_vector_type(8))) _Float16 f16x8;
typedef __attribute__((ext_vector_type(4))) float f32x4;
typedef __attribute__((ext_vector_type(16))) float f32x16;

#define NTOK 262144
#define NB 4096
#define NV 100000

__device__ __forceinline__ float sigm(float x){
  float e = __expf(-x);
  return __builtin_amdgcn_rcpf(1.0f + e);
}
// tanh(x) = 1 - 2/(1+e^{2x}); saturates, no clamp needed.
__device__ __forceinline__ float tanh_(float x){
  float e = __expf(2.f*x);
  float r = __builtin_amdgcn_rcpf(1.0f + e);
  return __builtin_fmaf(-2.0f, r, 1.0f);
}

__global__ void bias_k(const float* bWz,const float* bUzl,const float* bUzr,
                       const float* bWr,const float* bUrl,const float* bUrr,
                       const float* bWh,const float* bUhl,const float* bUhr, float* bc){
  int j = threadIdx.x;
  if (j < 128)      bc[j] = bWz[j]+bUzl[j]+bUzr[j];
  else if (j < 256){ int i=j-128; bc[j] = bWr[i]+bUrl[i]+bUrr[i]; }
  else if (j < 384){ int i=j-256; bc[j] = bWh[i]+bUhl[i]+bUhr[i]; }
}

// W (16x16 frag, K=128): Wf[((w*4+ks)*64+l)*8+j] = W[ks*32+(l>>4)*8+j][w*16+(l&15)]
// U (32x32 frag, K=256 interleaved): see header.
__global__ __launch_bounds__(256) void wprep_k(
    const float* Wz, const float* Wh,
    const float* Uzl,const float* Uzr,const float* Url,const float* Urr,
    const float* Uhl,const float* Uhr, half_t* wb){
  int idx = blockIdx.x*256 + threadIdx.x;           // 131072 total
  if (idx < 32768){                                  // Wz_f, Wh_f (16x16 layout)
    const float* W = (idx < 16384) ? Wz : Wh;
    int t = idx & 16383;
    int w = t >> 11, ks = (t >> 9) & 3, l = (t >> 3) & 63, j = t & 7;
    int n = w*16 + (l & 15);
    int k = ks*32 + ((l >> 4) << 3) + j;
    wb[idx] = (half_t)W[k*128 + n];
  } else {                                           // Uz_f, Ur_f, Uh_f (32x32 layout)
    int t = idx - 32768;
    int mat = t >> 15;                               // 0=z,1=r,2=h
    t &= 32767;
    int cg = t >> 13, ks = (t >> 9) & 15, l = (t >> 3) & 63, j = t & 7;
    int n = cg*32 + (l & 31);
    int kp = ks*16 + ((l >> 5) << 3) + j;            // 0..255 interleaved
    int k = kp >> 1;
    const float* U;
    if (mat == 0) U = (kp & 1) ? Uzr : Uzl;
    else if (mat == 1) U = (kp & 1) ? Urr : Url;
    else U = (kp & 1) ? Uhr : Uhl;
    wb[idx] = (half_t)U[k*128 + n];
  }
}

// Vocab table (16x16 path): t1[v] = (1-z)*tanh(xWh+bh), z=sigm(xWz+bz). Sequential rows.
template<int MT>
__global__ __launch_bounds__(512, 8) void h1tab_k(
    const float* __restrict__ emb,
    const half_t* __restrict__ Wz_f, const half_t* __restrict__ Wh_f,
    const float* __restrict__ bc, half_t* __restrict__ t1)
{
  __shared__ __align__(16) _Float16 xs[MT*16][136];
  const int tid = threadIdx.x;
  const int m0  = blockIdx.x*(MT*16);
  #pragma unroll
  for (int it = 0; it < MT; it++){
    int idx = it*512 + tid;
    int m = idx >> 5, c = idx & 31;
    int row = m0 + m; if (row >= NV) row = 0;
    float4 v = ((const float4*)(emb + (size_t)row*128))[c];
    union { half_t h[4]; ushort4 u; } p;
    p.h[0]=(half_t)v.x; p.h[1]=(half_t)v.y; p.h[2]=(half_t)v.z; p.h[3]=(half_t)v.w;
    *(ushort4*)&xs[m][c*4] = p.u;
  }
  __syncthreads();
  const int w = tid>>6, l = tid&63;
  const int lr = l&15, lk = (l>>4)*8, lq = (l>>4)*4;
  const int col = w*16 + lr;

  f32x4 zacc[MT] = {}; f32x4 hacc[MT] = {};
  const half_t* wzp = Wz_f + ((w*4)*64 + l)*8;
  const half_t* whp = Wh_f + ((w*4)*64 + l)*8;
  #pragma unroll
  for (int ks=0; ks<4; ks++){
    f16x8 bz = *(const f16x8*)(wzp + ks*512);
    f16x8 bh = *(const f16x8*)(whp + ks*512);
    #pragma unroll
    for (int mt=0; mt<MT; mt++){
      f16x8 a = *(const f16x8*)&xs[mt*16 + lr][ks*32 + lk];
      zacc[mt] = __builtin_amdgcn_mfma_f32_16x16x32_f16(a, bz, zacc[mt],0,0,0);
      hacc[mt] = __builtin_amdgcn_mfma_f32_16x16x32_f16(a, bh, hacc[mt],0,0,0);
    }
  }
  const float bzv = bc[col], bhv = bc[256+col];
  #pragma unroll
  for (int mt=0; mt<MT; mt++){
    #pragma unroll
    for (int q=0; q<4; q++){
      int row = m0 + mt*16 + lq + q;
      if (row < NV){
        float z  = sigm(zacc[mt][q] + bzv);
        float ht = tanh_(hacc[mt][q] + bhv);
        t1[(size_t)row*128 + col] = (half_t)((1.f-z)*ht);
      }
    }
  }
}

// Two-tile pipelined tree level. 256 thr = 4 waves (one col-group each); 2 tiles x 32 rows.
// GATHER=1: stage via tokens from row-major t1 (interleave in reg). GATHER=0: plain copy
// from pair-interleaved buffer. LAST=1: f32 row-major out; else pair-interleaved u32 out.
template<int GATHER, int LAST>
__global__ __launch_bounds__(256, 4) void tree_k(
    const half_t* __restrict__ hin, const int* __restrict__ tokens,
    uint* __restrict__ hout32, float* __restrict__ outf,
    const half_t* __restrict__ Uz_f, const half_t* __restrict__ Ur_f, const half_t* __restrict__ Uh_f,
    const float* __restrict__ bc)
{
  __shared__ __align__(16) _Float16 xs[2][32][264];   // 2 x 16.9 KB
  const int tid = threadIdx.x;
  const int w = tid >> 6, l = tid & 63;
  const int lc = l & 31, hi = l >> 5, lk8 = hi*8;
  const int cg = w;
  const int col = cg*32 + lc;
  const int m0 = blockIdx.x * 64;                     // 64 output rows per block
  const float bzv = bc[col], brv = bc[128+col], bhv = bc[256+col];
  const half_t* uzp = Uz_f + ((cg*16)*64 + l)*8;
  const half_t* urp = Ur_f + ((cg*16)*64 + l)*8;
  const half_t* uhp = Uh_f + ((cg*16)*64 + l)*8;

  uint4 stg[4];            // copy-mode staging regs
  uint2 sA[4], sB[4];      // gather-mode staging regs

  auto stage_load = [&](int t){
    if (GATHER){
      #pragma unroll
      for (int it = 0; it < 4; it++){
        int idx = it*256 + tid;
        int m = idx >> 5, c = idx & 31;
        int gm = m0 + t*32 + m;
        int tl = tokens[2*gm], tr = tokens[2*gm+1];
        sA[it] = *(const uint2*)(hin + (size_t)tl*128 + c*4);
        sB[it] = *(const uint2*)(hin + (size_t)tr*128 + c*4);
      }
    } else {
      const uint* src = (const uint*)hin + (size_t)(m0 + t*32)*128;
      #pragma unroll
      for (int it = 0; it < 4; it++){
        stg[it] = ((const uint4*)src)[it*256 + tid];
      }
    }
  };
  auto stage_write = [&](int t){
    #pragma unroll
    for (int it = 0; it < 4; it++){
      int idx = it*256 + tid;
      int m = idx >> 5, c = idx & 31;
      uint4 o;
      if (GATHER){
        o.x = (sA[it].x & 0xFFFFu) | (sB[it].x << 16);
        o.y = (sA[it].x >> 16)     | (sB[it].x & 0xFFFF0000u);
        o.z = (sA[it].y & 0xFFFFu) | (sB[it].y << 16);
        o.w = (sA[it].y >> 16)     | (sB[it].y & 0xFFFF0000u);
      } else {
        o = stg[it];
      }
      *(uint4*)&xs[t][m][c*8] = o;
    }
  };
  auto gemm_zr = [&](int t, f32x16& za, f32x16& ra){
    #pragma unroll
    for (int ks = 0; ks < 16; ks++){
      f16x8 bz = *(const f16x8*)(uzp + ks*512);
      f16x8 br = *(const f16x8*)(urp + ks*512);
      f16x8 a  = *(const f16x8*)&xs[t][lc][ks*16 + lk8];
      za = __builtin_amdgcn_mfma_f32_32x32x16_f16(a, bz, za,0,0,0);
      ra = __builtin_amdgcn_mfma_f32_32x32x16_f16(a, br, ra,0,0,0);
    }
  };
  auto gemm_h = [&](int t, f32x16& ha){
    #pragma unroll
    for (int ks = 0; ks < 16; ks++){
      f16x8 bh = *(const f16x8*)(uhp + ks*512);
      f16x8 a  = *(const f16x8*)&xs[t][lc][ks*16 + lk8];
      ha = __builtin_amdgcn_mfma_f32_32x32x16_f16(a, bh, ha,0,0,0);
    }
  };
  union U16 { half_t h[16]; uint u[8]; };
  auto ew = [&](int t, const f32x16& za, const f32x16& ra, uint* zp, uint* sp){
    U16 pz, ps;
    #pragma unroll
    for (int r = 0; r < 16; r++){
      int row = (r&3) + 8*(r>>2) + 4*hi;
      union { uint u; f16x2 h2; } io;
      io.u = *(uint*)&xs[t][row][2*col];
      half_t s = (half_t)(io.h2[0] + io.h2[1]);
      float z  = sigm(za[r] + bzv);
      float rv = sigm(ra[r] + brv);
      half_t rh = (half_t)rv;
      f16x2 r2; r2[0]=rh; r2[1]=rh;
      io.h2 = io.h2 * r2;                 // v_pk_mul_f16
      *(uint*)&xs[t][row][2*col] = io.u;
      pz.h[r] = (half_t)z;
      ps.h[r] = s;
    }
    #pragma unroll
    for (int i = 0; i < 8; i++){ zp[i]=pz.u[i]; sp[i]=ps.u[i]; }
  };
  auto epi = [&](int t, const f32x16& ha, const uint* zp, const uint* sp){
    U16 pz, ps;
    #pragma unroll
    for (int i = 0; i < 8; i++){ pz.u[i]=zp[i]; ps.u[i]=sp[i]; }
    #pragma unroll
    for (int p = 0; p < 8; p++){
      int r0 = 2*p;
      int row0 = 2*(p&1) + 8*(p>>1) + 4*hi;
      float ht0 = tanh_(ha[r0]   + bhv);
      float ht1 = tanh_(ha[r0+1] + bhv);
      float z0 = (float)pz.h[r0],   s0 = (float)ps.h[r0];
      float z1 = (float)pz.h[r0+1], s1 = (float)ps.h[r0+1];
      float o0 = __builtin_fmaf(z0, s0 - ht0, ht0);
      float o1 = __builtin_fmaf(z1, s1 - ht1, ht1);
      if (LAST){
        outf[(size_t)(m0 + t*32 + row0)*128 + col]     = o0;
        outf[(size_t)(m0 + t*32 + row0 + 1)*128 + col] = o1;
      } else {
        union { uint u; f16x2 h2; } pk;
        pk.h2[0] = (half_t)o0; pk.h2[1] = (half_t)o1;
        hout32[(size_t)((m0 + t*32 + row0) >> 1)*128 + col] = pk.u;
      }
    }
  };

  // ---- pipeline ----
  stage_load(0); stage_write(0);
  __syncthreads();

  f32x16 za0 = {}, ra0 = {};
  stage_load(1);                 // VMEM issues early, hides under G1(T0)
  gemm_zr(0, za0, ra0);
  stage_write(1);
  __syncthreads();

  uint zp0[8], sp0[8];
  f32x16 za1 = {}, ra1 = {};
  gemm_zr(1, za1, ra1);          // MFMA stream ...
  ew(0, za0, ra0, zp0, sp0);     // ... mixed with VALU/LDS stream
  __syncthreads();

  uint zp1[8], sp1[8];
  f32x16 h0 = {};
  gemm_h(0, h0);
  ew(1, za1, ra1, zp1, sp1);
  __syncthreads();

  f32x16 h1 = {};
  gemm_h(1, h1);
  epi(0, h0, zp0, sp0);
  epi(1, h1, zp1, sp1);
}

extern "C" void kernel_launch(void* const* d_in, const int* in_sizes, int n_in,
                              void* d_out, int out_size, void* d_ws, size_t ws_size,
                              hipStream_t stream) {
  const int*   tokens = (const int*)  d_in[0];
  const float* emb    = (const float*)d_in[1];
  const float* Wz  = (const float*)d_in[2];  const float* bWz  = (const float*)d_in[3];
  const float* Uzl = (const float*)d_in[4];  const float* bUzl = (const float*)d_in[5];
  const float* Uzr = (const float*)d_in[6];  const float* bUzr = (const float*)d_in[7];
  const float* Wr  = (const float*)d_in[8];  const float* bWr  = (const float*)d_in[9];
  const float* Url = (const float*)d_in[10]; const float* bUrl = (const float*)d_in[11];
  const float* Urr = (const float*)d_in[12]; const float* bUrr = (const float*)d_in[13];
  const float* Wh  = (const float*)d_in[14]; const float* bWh  = (const float*)d_in[15];
  const float* Uhl = (const float*)d_in[16]; const float* bUhl = (const float*)d_in[17];
  const float* Uhr = (const float*)d_in[18]; const float* bUhr = (const float*)d_in[19];

  float*  bc = (float*)d_ws;
  half_t* wb = (half_t*)((char*)d_ws + 4096);
  half_t* Wz_f = wb;
  half_t* Wh_f = wb + 16384;
  half_t* Uz_f = wb + 32768;
  half_t* Ur_f = wb + 65536;
  half_t* Uh_f = wb + 98304;
  half_t* t1 = (half_t*)((char*)d_ws + (1<<20));     // 100000*128 f16 = 25.6 MB
  half_t* hA = t1 + (size_t)NV*128;                  // pair-interleaved, 33.5 MB max
  half_t* hB = hA + (size_t)(NTOK/2)*128;            // 16.8 MB max

  bias_k<<<1, 384, 0, stream>>>(bWz,bUzl,bUzr,bWr,bUrl,bUrr,bWh,bUhl,bUhr, bc);
  wprep_k<<<512, 256, 0, stream>>>(Wz,Wh,Uzl,Uzr,Url,Urr,Uhl,Uhr, wb);

  h1tab_k<4><<<(NV + 63)/64, 512, 0, stream>>>(emb, Wz_f, Wh_f, bc, t1);

  float* outf = (float*)d_out;
  // L1: gather from t1 (row-major), M=131072 -> pair-interleaved hA
  tree_k<1,0><<<2048, 256, 0, stream>>>(t1, tokens, (uint*)hA, outf, Uz_f, Ur_f, Uh_f, bc);
  // L2..L5: pair-interleaved in/out
  tree_k<0,0><<<1024, 256, 0, stream>>>(hA, tokens, (uint*)hB, outf, Uz_f, Ur_f, Uh_f, bc); // L2 65536
  tree_k<0,0><<<512,  256, 0, stream>>>(hB, tokens, (uint*)hA, outf, Uz_f, Ur_f, Uh_f, bc); // L3 32768
  tree_k<0,0><<<256,  256, 0, stream>>>(hA, tokens, (uint*)hB, outf, Uz_f, Ur_f, Uh_f, bc); // L4 16384
  tree_k<0,0><<<128,  256, 0, stream>>>(hB, tokens, (uint*)hA, outf, Uz_f, Ur_f, Uh_f, bc); // L5 8192
  // L6: f32 row-major to d_out
  tree_k<0,1><<<64,   256, 0, stream>>>(hA, tokens, (uint*)hB, outf, Uz_f, Ur_f, Uh_f, bc); // L6 4096
}